// Round 5
// baseline (121.643 us; speedup 1.0000x reference)
//
#include <hip/hip_runtime.h>

typedef unsigned short u16;
typedef __attribute__((ext_vector_type(4))) float f32x4;
typedef __attribute__((ext_vector_type(4))) int i32x4;
typedef __attribute__((ext_vector_type(8))) short short8;
typedef __attribute__((ext_vector_type(8))) __bf16 bf16x8;
typedef __attribute__((ext_vector_type(4))) unsigned short u16x4;

#define BATCH 16384
#define NINP 256
#define HID 1024
#define NOUT 16

// ---------- helpers ----------
__device__ __forceinline__ u16 f2bf(float f) {
  unsigned u = __builtin_bit_cast(unsigned, f);
  u += 0x7FFFu + ((u >> 16) & 1u);   // round-to-nearest-even
  return (u16)(u >> 16);
}
__device__ __forceinline__ f32x4 mfma_s8(short8 a, short8 b, f32x4 c) {
  return __builtin_amdgcn_mfma_f32_16x16x32_bf16(
      __builtin_bit_cast(bf16x8, a), __builtin_bit_cast(bf16x8, b), c, 0, 0, 0);
}
__device__ __forceinline__ f32x4 mfma_bb(bf16x8 a, bf16x8 b, f32x4 c) {
  return __builtin_amdgcn_mfma_f32_16x16x32_bf16(a, b, c, 0, 0, 0);
}
__device__ __forceinline__ void gload_lds16(const void* g, void* l) {
  __builtin_amdgcn_global_load_lds(
      (const __attribute__((address_space(1))) void*)g,
      (__attribute__((address_space(3))) void*)l, 16, 0, 0);
}

// ---------- workspace layout (bytes) ----------
// part (16 MB) aliases H0 (32 MB): H0 is dead once gemm2 has run; k_uni
// (which writes part) launches after gemm2 on the same stream.
static const size_t OFF_H0   = 0;          // 33,554,432  H0 bf16 [16384][1024]
static const size_t OFF_PART = 0;          // 16,777,216  part f32 [16][16384][16]
static const size_t OFF_H1   = 33554432;   // 33,554,432  H1 bf16
static const size_t OFF_XB   = 33554432;   //  8,388,608  x bf16 (aliases H1: dead before gemm2 writes H1)
static const size_t OFF_W0T  = 67108864;   //    524,288  W0^T bf16 [1024][256]
static const size_t OFF_W1T  = 67633152;   //  2,097,152  W1^T bf16 [1024][1024]
static const size_t OFF_W2T  = 69730304;   //     32,768  W2^T bf16 [16][1024]
static const size_t OFF_UWP  = 69763072;   //  1,048,576  packed uni blobs, 4096B/feature
static const size_t OFF_CB   = 70811648;   //        256  cb f32 [16]

// Blob layout per feature i (byte offsets within uwp + i*4096):
//    0..128   uw1[32] f32
//  128..256   ub1[32] f32
//  256..384   ub2[32] f32
//  384..512   pad
//  512..1536  puw2 lo=0: lane L holds uw2t[row=L&15      ][col=(L>>4)*8+j], j=0..7 bf16
// 1536..2560  puw2 lo=1: lane L holds uw2t[row=16+(L&15) ][col=(L>>4)*8+j]
// 2560..3584  puw3:      lane L holds uw3p[o2=L&15][slot=(L>>4)*8+j]
// 3584..4096  pad

// ---------- merged prep: transposes + converts + packing ----------
__global__ __launch_bounds__(256) void k_prep(
    const float* __restrict__ x,
    const float* __restrict__ W0, const float* __restrict__ W1,
    const float* __restrict__ W2,
    const float* __restrict__ uw1, const float* __restrict__ ub1,
    const float* __restrict__ uw2, const float* __restrict__ ub2,
    const float* __restrict__ uw3, const float* __restrict__ b2,
    const float* __restrict__ ub3,
    u16* __restrict__ xb,
    u16* __restrict__ W0T, u16* __restrict__ W1T, u16* __restrict__ W2T,
    char* __restrict__ uwp, float* __restrict__ cb)
{
  __shared__ float tile[32][33];
  const int bid = blockIdx.x;
  const int tid = threadIdx.x;

  if (bid < 1312) {                       // weight transposes f32[K][N] -> bf16[N][K]
    const float* src; u16* dst; int K, N, kb, ob;
    if (bid < 256)       { src = W0; dst = W0T; K = 256;  N = 1024; int t = bid;        kb = (t & 7) * 32;  ob = (t >> 3) * 32; }
    else if (bid < 1280) { src = W1; dst = W1T; K = 1024; N = 1024; int t = bid - 256;  kb = (t & 31) * 32; ob = (t >> 5) * 32; }
    else                 { src = W2; dst = W2T; K = 1024; N = 16;   int t = bid - 1280; kb = t * 32;        ob = 0; }
    const int tx = tid & 31, ty = tid >> 5;
    for (int r = ty; r < 32; r += 8)
      if (ob + tx < N) tile[r][tx] = src[(size_t)(kb + r) * N + ob + tx];
    __syncthreads();
    for (int r = ty; r < 32; r += 8)
      if (ob + r < N) dst[(size_t)(ob + r) * K + kb + tx] = f2bf(tile[tx][r]);
  } else if (bid < 5408) {                // x -> bf16
    const int idx = ((bid - 1312) * 256 + tid) * 4;
    const float4 v = *(const float4*)&x[idx];
    u16x4 o4 = { f2bf(v.x), f2bf(v.y), f2bf(v.z), f2bf(v.w) };
    *(u16x4*)&xb[idx] = o4;
  } else if (bid < 5664) {                // uw2 -> puw2 fragments
    const int e = ((bid - 5408) * 256 + tid) * 4;
    const float4 v = *(const float4*)&uw2[e];
    const int i = e >> 10, f = (e >> 5) & 31, o = e & 31;
    const float vv[4] = { v.x, v.y, v.z, v.w };
    u16* blob16 = (u16*)(uwp + (size_t)i * 4096);
#pragma unroll
    for (int d = 0; d < 4; ++d) {
      const int oo = o + d;
      const int lane = ((f >> 3) << 4) | (oo & 15);
      blob16[256 + (oo >> 4) * 512 + lane * 8 + (f & 7)] = f2bf(vv[d]);
    }
  } else if (bid < 5792) {                // uw3 -> puw3 fragments (k-slot perm)
    const int e = ((bid - 5664) * 256 + tid) * 4;
    const float4 v = *(const float4*)&uw3[e];
    const int i = e >> 9, f = (e >> 4) & 31, o2 = e & 15;
    const int s = (f < 16) ? (((f >> 2) << 3) + (f & 3))
                           : ((((f - 16) >> 2) << 3) + 4 + (f & 3));
    const float vv[4] = { v.x, v.y, v.z, v.w };
    u16* blob16 = (u16*)(uwp + (size_t)i * 4096);
#pragma unroll
    for (int d = 0; d < 4; ++d)
      blob16[1280 + ((s >> 3) * 16 + o2 + d) * 8 + (s & 7)] = f2bf(vv[d]);
  } else if (bid < 5816) {                // uw1/ub1/ub2 f32 copy into blobs
    const int e4 = (bid - 5792) * 256 + tid;      // float4 index, 0..6143
    const int i = e4 / 24, r4 = e4 % 24;
    const float* src = (r4 < 8)  ? &uw1[i * 32 + r4 * 4]
                     : (r4 < 16) ? &ub1[i * 32 + (r4 - 8) * 4]
                                 : &ub2[i * 32 + (r4 - 16) * 4];
    *(float4*)(uwp + (size_t)i * 4096 + r4 * 16) = *(const float4*)src;
  } else {                                // cb[o] = b2[o] + sum_i ub3[i][o]
    __shared__ float red[16][16];
    const int ig = tid >> 4, o = tid & 15;
    float s = 0.f;
#pragma unroll
    for (int k = 0; k < 16; ++k) s += ub3[(ig * 16 + k) * 16 + o];
    red[ig][o] = s;
    __syncthreads();
    if (tid < 16) {
      float t = b2[tid];
#pragma unroll
      for (int k = 0; k < 16; ++k) t += red[k][tid];
      cb[tid] = t;
    }
  }
}

// ---------- MFMA GEMM: C = relu(A @ B^T + bias), bf16 in/out, fp32 acc ----------
__global__ __launch_bounds__(256, 2) void k_gemm(
    const u16* __restrict__ A, const u16* __restrict__ BT,
    const float* __restrict__ bias, u16* __restrict__ C,
    int M, int N, int K)
{
  const int tid = threadIdx.x;
  const int lane = tid & 63, wid = tid >> 6;
  const int l15 = lane & 15, g = lane >> 4;
  const int nbn = N >> 7;
  const int nwg = gridDim.x;
  int logical = blockIdx.x;
  if ((nwg & 7) == 0) {                       // bijective XCD swizzle
    const int q = nwg >> 3;
    logical = (logical & 7) * q + (logical >> 3);
  }
  const int bm = logical / nbn, bn = logical % nbn;
  const size_t rb = (size_t)bm * 128, cbase = (size_t)bn * 128;

  __shared__ __align__(16) u16 As[128 * 32];
  __shared__ __align__(16) u16 Bs[128 * 32];

  const int wr = (wid >> 1) * 64, wc = (wid & 1) * 64;
  f32x4 acc[4][4] = {};

  for (int kt = 0; kt < K; kt += 32) {
#pragma unroll
    for (int it = 0; it < 2; ++it) {
      const int s = it * 256 + tid;
      const int row = s >> 2, kc = s & 3;
      gload_lds16(&A[(rb + row) * K + kt + kc * 8], &As[s * 8]);
      gload_lds16(&BT[(cbase + row) * K + kt + kc * 8], &Bs[s * 8]);
    }
    __syncthreads();
    short8 a[4], b[4];
#pragma unroll
    for (int m = 0; m < 4; ++m)
      a[m] = *(const short8*)&As[(wr + m * 16 + l15) * 32 + g * 8];
#pragma unroll
    for (int n = 0; n < 4; ++n)
      b[n] = *(const short8*)&Bs[(wc + n * 16 + l15) * 32 + g * 8];
#pragma unroll
    for (int m = 0; m < 4; ++m)
#pragma unroll
      for (int n = 0; n < 4; ++n)
        acc[m][n] = mfma_s8(a[m], b[n], acc[m][n]);
    __syncthreads();
  }

#pragma unroll
  for (int n = 0; n < 4; ++n) {
    const int col = (int)cbase + wc + n * 16 + l15;
    const float bv = bias[col];
#pragma unroll
    for (int m = 0; m < 4; ++m) {
#pragma unroll
      for (int r = 0; r < 4; ++r) {
        const int row = (int)rb + wr + m * 16 + g * 4 + r;
        float v = acc[m][n][r] + bv;
        v = fmaxf(v, 0.f);
        C[(size_t)row * N + col] = f2bf(v);
      }
    }
  }
}

// ---------- uni MLPs + final layer (H1 @ W2^T), 16 chunks ----------
// grid = 2048: blockIdx = rowblk*16 + chunk -> 8 blocks/CU, 32 waves/CU.
// Block = 4 waves x 32 batch rows (2 frags). Chunk owns features
// [16c, 16c+16) and K-range [64c, 64c+64) of H1@W2.
// All MFMAs operand-swapped: D[out][batch]; b = lane&15, out = 4*(lane>>4)+r.
// ub2 folded into the layer-2 MFMA accumulator init.
__global__ __launch_bounds__(256, 8) void k_uni(
    const float* __restrict__ x,
    const char* __restrict__ uwp,
    const u16* __restrict__ H1, const u16* __restrict__ W2T,
    float* __restrict__ part)
{
  const int tid = threadIdx.x, lane = tid & 63, wid = tid >> 6;
  const int l15 = lane & 15, g = lane >> 4;
  const int chunk = blockIdx.x & 15, rowblk = blockIdx.x >> 4;
  const int rb_blk = rowblk * 128;
  const int rb = rb_blk + wid * 32;
  const int i0 = chunk * 16;

  __shared__ __align__(16) float xt[128][20];   // x tile f32, padded
  {
    const int r0 = tid >> 1, c8 = (tid & 1) * 8;
    const float* s = &x[(size_t)(rb_blk + r0) * NINP + i0 + c8];
    *(float4*)&xt[r0][c8]     = *(const float4*)s;
    *(float4*)&xt[r0][c8 + 4] = *(const float4*)(s + 4);
  }
  __syncthreads();

  const f32x4 zero4 = {0.f, 0.f, 0.f, 0.f};
  f32x4 acc0 = zero4, acc1 = zero4;
  const float* xr0 = &xt[wid * 32 + l15][0];
  const float* xr1 = &xt[wid * 32 + 16 + l15][0];
  const char* bp = uwp + (size_t)i0 * 4096;

#pragma unroll 2
  for (int ii = 0; ii < 16; ++ii, bp += 4096) {
    const f32x4 w1lo = *(const f32x4*)(bp + g * 32);
    const f32x4 w1hi = *(const f32x4*)(bp + g * 32 + 16);
    const f32x4 b1lo = *(const f32x4*)(bp + 128 + g * 32);
    const f32x4 b1hi = *(const f32x4*)(bp + 128 + g * 32 + 16);
    const f32x4 bb0  = *(const f32x4*)(bp + 256 + g * 16);
    const f32x4 bb1  = *(const f32x4*)(bp + 320 + g * 16);
    const bf16x8 bv0 = *(const bf16x8*)(bp + 512 + lane * 16);
    const bf16x8 bv1 = *(const bf16x8*)(bp + 1536 + lane * 16);
    const bf16x8 b3  = *(const bf16x8*)(bp + 2560 + lane * 16);
    const float xv0 = xr0[ii], xv1 = xr1[ii];

    // layer 1 (rank-1): h1[b][f=g*8+j] as B-frag, two batch frags
    bf16x8 af0, af1;
#pragma unroll
    for (int j = 0; j < 4; ++j) {
      af0[j]     = (__bf16)fmaxf(fmaf(xv0, w1lo[j], b1lo[j]), 0.f);
      af0[4 + j] = (__bf16)fmaxf(fmaf(xv0, w1hi[j], b1hi[j]), 0.f);
      af1[j]     = (__bf16)fmaxf(fmaf(xv1, w1lo[j], b1lo[j]), 0.f);
      af1[4 + j] = (__bf16)fmaxf(fmaf(xv1, w1hi[j], b1hi[j]), 0.f);
    }

    // layer 2 swapped: D2[o][b], o = 4g+r (+16 for d1*), bias in C-input
    const f32x4 d00 = mfma_bb(bv0, af0, bb0);
    const f32x4 d10 = mfma_bb(bv1, af0, bb1);
    const f32x4 d01 = mfma_bb(bv0, af1, bb0);
    const f32x4 d11 = mfma_bb(bv1, af1, bb1);

    // h2 = relu(D2), lane-local; k-slots match uw3p permutation
    bf16x8 h20, h21;
#pragma unroll
    for (int j = 0; j < 4; ++j) {
      h20[j]     = (__bf16)fmaxf(d00[j], 0.f);
      h20[4 + j] = (__bf16)fmaxf(d10[j], 0.f);
      h21[j]     = (__bf16)fmaxf(d01[j], 0.f);
      h21[4 + j] = (__bf16)fmaxf(d11[j], 0.f);
    }

    // layer 3 swapped: acc[o2][b] += uw3p @ h2
    acc0 = mfma_bb(b3, h20, acc0);
    acc1 = mfma_bb(b3, h21, acc1);
  }

  // final-layer K-chunk (K=64): acc[o2][b] += W2T @ H1^T
  {
    const int kb0 = chunk * 64;
#pragma unroll
    for (int kk = 0; kk < 2; ++kk) {
      const int kb = kb0 + kk * 32;
      const bf16x8 a0 = __builtin_bit_cast(bf16x8,
          *(const i32x4*)&H1[(size_t)(rb + l15) * HID + kb + g * 8]);
      const bf16x8 a1 = __builtin_bit_cast(bf16x8,
          *(const i32x4*)&H1[(size_t)(rb + 16 + l15) * HID + kb + g * 8]);
      const bf16x8 bv = __builtin_bit_cast(bf16x8,
          *(const i32x4*)&W2T[l15 * HID + kb + g * 8]);
      acc0 = mfma_bb(bv, a0, acc0);
      acc1 = mfma_bb(bv, a1, acc1);
    }
  }

  // acc*[r] = u[b=l15(+16)][o2=4g+r] -> contiguous f32x4 stores
  float* p = part + ((size_t)chunk * BATCH + rb) * NOUT;
  *(f32x4*)&p[l15 * 16 + g * 4] = acc0;
  *(f32x4*)&p[(16 + l15) * 16 + g * 4] = acc1;
}

// ---------- reduce 16 partials + cb -> out ----------
__global__ __launch_bounds__(256) void k_reduce(
    const float* __restrict__ part, const float* __restrict__ cb,
    float* __restrict__ out)
{
  const int j4 = blockIdx.x * 256 + threadIdx.x;   // 65536 float4's
  const float4 c = ((const float4*)cb)[j4 & 3];
  const float4* p = (const float4*)part;
  float rx = c.x, ry = c.y, rz = c.z, rw = c.w;
#pragma unroll
  for (int cc = 0; cc < 16; ++cc) {
    const float4 a = p[cc * 65536 + j4];
    rx += a.x; ry += a.y; rz += a.z; rw += a.w;
  }
  float4 r; r.x = rx; r.y = ry; r.z = rz; r.w = rw;
  ((float4*)out)[j4] = r;
}

extern "C" void kernel_launch(void* const* d_in, const int* in_sizes, int n_in,
                              void* d_out, int out_size, void* d_ws, size_t ws_size,
                              hipStream_t stream) {
  (void)in_sizes; (void)n_in; (void)out_size; (void)ws_size;
  const float* x   = (const float*)d_in[0];
  const float* W0  = (const float*)d_in[1];
  const float* b0  = (const float*)d_in[2];
  const float* W1  = (const float*)d_in[3];
  const float* b1  = (const float*)d_in[4];
  const float* W2  = (const float*)d_in[5];
  const float* b2  = (const float*)d_in[6];
  const float* uw1 = (const float*)d_in[7];
  const float* ub1 = (const float*)d_in[8];
  const float* uw2 = (const float*)d_in[9];
  const float* ub2 = (const float*)d_in[10];
  const float* uw3 = (const float*)d_in[11];
  const float* ub3 = (const float*)d_in[12];
  float* out = (float*)d_out;

  char* ws = (char*)d_ws;
  u16*   H0   = (u16*)(ws + OFF_H0);
  u16*   H1   = (u16*)(ws + OFF_H1);
  u16*   xb   = (u16*)(ws + OFF_XB);
  u16*   W0T  = (u16*)(ws + OFF_W0T);
  u16*   W1T  = (u16*)(ws + OFF_W1T);
  u16*   W2T  = (u16*)(ws + OFF_W2T);
  char*  uwp  = (char*)(ws + OFF_UWP);
  float* cb   = (float*)(ws + OFF_CB);
  float* part = (float*)(ws + OFF_PART);

  k_prep<<<5817, 256, 0, stream>>>(x, W0, W1, W2, uw1, ub1, uw2, ub2, uw3,
                                   b2, ub3, xb, W0T, W1T, W2T, uwp, cb);
  k_gemm<<<1024, 256, 0, stream>>>(xb, W0T, b0, H0, BATCH, HID, NINP);
  k_gemm<<<1024, 256, 0, stream>>>(H0, W1T, b1, H1, BATCH, HID, HID);
  k_uni<<<2048, 256, 0, stream>>>(x, uwp, H1, W2T, part);
  k_reduce<<<256, 256, 0, stream>>>(part, cb, out);
}

// Round 6
// 105.379 us; speedup vs baseline: 1.1543x; 1.1543x over previous
//
#include <hip/hip_runtime.h>

typedef unsigned short u16;
typedef __attribute__((ext_vector_type(4))) float f32x4;
typedef __attribute__((ext_vector_type(4))) int i32x4;
typedef __attribute__((ext_vector_type(8))) short short8;
typedef __attribute__((ext_vector_type(8))) __bf16 bf16x8;
typedef __attribute__((ext_vector_type(4))) unsigned short u16x4;

#define BATCH 16384
#define NINP 256
#define HID 1024
#define NOUT 16

// ---------- helpers ----------
__device__ __forceinline__ u16 f2bf(float f) {
  unsigned u = __builtin_bit_cast(unsigned, f);
  u += 0x7FFFu + ((u >> 16) & 1u);   // round-to-nearest-even
  return (u16)(u >> 16);
}
__device__ __forceinline__ f32x4 mfma_s8(short8 a, short8 b, f32x4 c) {
  return __builtin_amdgcn_mfma_f32_16x16x32_bf16(
      __builtin_bit_cast(bf16x8, a), __builtin_bit_cast(bf16x8, b), c, 0, 0, 0);
}
__device__ __forceinline__ f32x4 mfma_bb(bf16x8 a, bf16x8 b, f32x4 c) {
  return __builtin_amdgcn_mfma_f32_16x16x32_bf16(a, b, c, 0, 0, 0);
}
__device__ __forceinline__ void gload_lds16(const void* g, void* l) {
  __builtin_amdgcn_global_load_lds(
      (const __attribute__((address_space(1))) void*)g,
      (__attribute__((address_space(3))) void*)l, 16, 0, 0);
}

// ---------- workspace layout (bytes) ----------
// part (8.4 MB) aliases H0 (32 MB): H0 is dead once gemm2 has run; k_uni
// (which writes part) launches after gemm2 on the same stream.
static const size_t OFF_H0   = 0;          // 33,554,432  H0 bf16 [16384][1024]
static const size_t OFF_PART = 0;          //  8,388,608  part f32 [8][16384][16]
static const size_t OFF_H1   = 33554432;   // 33,554,432  H1 bf16
static const size_t OFF_XB   = 33554432;   //  8,388,608  x bf16 (aliases H1: dead before gemm2 writes H1)
static const size_t OFF_W0T  = 67108864;   //    524,288  W0^T bf16 [1024][256]
static const size_t OFF_W1T  = 67633152;   //  2,097,152  W1^T bf16 [1024][1024]
static const size_t OFF_W2T  = 69730304;   //     32,768  W2^T bf16 [16][1024]
static const size_t OFF_UWP  = 69763072;   //  1,048,576  packed uni blobs, 4096B/feature
static const size_t OFF_CB   = 70811648;   //        256  cb f32 [16]

// Blob layout per feature i (byte offsets within uwp + i*4096):
//    0..128   uw1[32] f32
//  128..256   ub1[32] f32
//  256..384   ub2[32] f32
//  384..512   pad
//  512..1536  puw2 lo=0: lane L holds uw2t[row=L&15      ][col=(L>>4)*8+j], j=0..7 bf16
// 1536..2560  puw2 lo=1: lane L holds uw2t[row=16+(L&15) ][col=(L>>4)*8+j]
// 2560..3584  puw3:      lane L holds uw3p[o2=L&15][slot=(L>>4)*8+j]
// 3584..4096  pad
// Blob is exactly 4096 B: one global_load_lds(16B) per thread stages it.

// ---------- merged prep: transposes + converts + packing ----------
__global__ __launch_bounds__(256) void k_prep(
    const float* __restrict__ x,
    const float* __restrict__ W0, const float* __restrict__ W1,
    const float* __restrict__ W2,
    const float* __restrict__ uw1, const float* __restrict__ ub1,
    const float* __restrict__ uw2, const float* __restrict__ ub2,
    const float* __restrict__ uw3, const float* __restrict__ b2,
    const float* __restrict__ ub3,
    u16* __restrict__ xb,
    u16* __restrict__ W0T, u16* __restrict__ W1T, u16* __restrict__ W2T,
    char* __restrict__ uwp, float* __restrict__ cb)
{
  __shared__ float tile[32][33];
  const int bid = blockIdx.x;
  const int tid = threadIdx.x;

  if (bid < 1312) {                       // weight transposes f32[K][N] -> bf16[N][K]
    const float* src; u16* dst; int K, N, kb, ob;
    if (bid < 256)       { src = W0; dst = W0T; K = 256;  N = 1024; int t = bid;        kb = (t & 7) * 32;  ob = (t >> 3) * 32; }
    else if (bid < 1280) { src = W1; dst = W1T; K = 1024; N = 1024; int t = bid - 256;  kb = (t & 31) * 32; ob = (t >> 5) * 32; }
    else                 { src = W2; dst = W2T; K = 1024; N = 16;   int t = bid - 1280; kb = t * 32;        ob = 0; }
    const int tx = tid & 31, ty = tid >> 5;
    for (int r = ty; r < 32; r += 8)
      if (ob + tx < N) tile[r][tx] = src[(size_t)(kb + r) * N + ob + tx];
    __syncthreads();
    for (int r = ty; r < 32; r += 8)
      if (ob + r < N) dst[(size_t)(ob + r) * K + kb + tx] = f2bf(tile[tx][r]);
  } else if (bid < 5408) {                // x -> bf16
    const int idx = ((bid - 1312) * 256 + tid) * 4;
    const float4 v = *(const float4*)&x[idx];
    u16x4 o4 = { f2bf(v.x), f2bf(v.y), f2bf(v.z), f2bf(v.w) };
    *(u16x4*)&xb[idx] = o4;
  } else if (bid < 5664) {                // uw2 -> puw2 fragments
    const int e = ((bid - 5408) * 256 + tid) * 4;
    const float4 v = *(const float4*)&uw2[e];
    const int i = e >> 10, f = (e >> 5) & 31, o = e & 31;
    const float vv[4] = { v.x, v.y, v.z, v.w };
    u16* blob16 = (u16*)(uwp + (size_t)i * 4096);
#pragma unroll
    for (int d = 0; d < 4; ++d) {
      const int oo = o + d;
      const int lane = ((f >> 3) << 4) | (oo & 15);
      blob16[256 + (oo >> 4) * 512 + lane * 8 + (f & 7)] = f2bf(vv[d]);
    }
  } else if (bid < 5792) {                // uw3 -> puw3 fragments (k-slot perm)
    const int e = ((bid - 5664) * 256 + tid) * 4;
    const float4 v = *(const float4*)&uw3[e];
    const int i = e >> 9, f = (e >> 4) & 31, o2 = e & 15;
    const int s = (f < 16) ? (((f >> 2) << 3) + (f & 3))
                           : ((((f - 16) >> 2) << 3) + 4 + (f & 3));
    const float vv[4] = { v.x, v.y, v.z, v.w };
    u16* blob16 = (u16*)(uwp + (size_t)i * 4096);
#pragma unroll
    for (int d = 0; d < 4; ++d)
      blob16[1280 + ((s >> 3) * 16 + o2 + d) * 8 + (s & 7)] = f2bf(vv[d]);
  } else if (bid < 5816) {                // uw1/ub1/ub2 f32 copy into blobs
    const int e4 = (bid - 5792) * 256 + tid;      // float4 index, 0..6143
    const int i = e4 / 24, r4 = e4 % 24;
    const float* src = (r4 < 8)  ? &uw1[i * 32 + r4 * 4]
                     : (r4 < 16) ? &ub1[i * 32 + (r4 - 8) * 4]
                                 : &ub2[i * 32 + (r4 - 16) * 4];
    *(float4*)(uwp + (size_t)i * 4096 + r4 * 16) = *(const float4*)src;
  } else {                                // cb[o] = b2[o] + sum_i ub3[i][o]
    __shared__ float red[16][16];
    const int ig = tid >> 4, o = tid & 15;
    float s = 0.f;
#pragma unroll
    for (int k = 0; k < 16; ++k) s += ub3[(ig * 16 + k) * 16 + o];
    red[ig][o] = s;
    __syncthreads();
    if (tid < 16) {
      float t = b2[tid];
#pragma unroll
      for (int k = 0; k < 16; ++k) t += red[k][tid];
      cb[tid] = t;
    }
  }
}

// ---------- MFMA GEMM: C = relu(A @ B^T + bias), bf16 in/out, fp32 acc ----------
__global__ __launch_bounds__(256, 2) void k_gemm(
    const u16* __restrict__ A, const u16* __restrict__ BT,
    const float* __restrict__ bias, u16* __restrict__ C,
    int M, int N, int K)
{
  const int tid = threadIdx.x;
  const int lane = tid & 63, wid = tid >> 6;
  const int l15 = lane & 15, g = lane >> 4;
  const int nbn = N >> 7;
  const int nwg = gridDim.x;
  int logical = blockIdx.x;
  if ((nwg & 7) == 0) {                       // bijective XCD swizzle
    const int q = nwg >> 3;
    logical = (logical & 7) * q + (logical >> 3);
  }
  const int bm = logical / nbn, bn = logical % nbn;
  const size_t rb = (size_t)bm * 128, cbase = (size_t)bn * 128;

  __shared__ __align__(16) u16 As[128 * 32];
  __shared__ __align__(16) u16 Bs[128 * 32];

  const int wr = (wid >> 1) * 64, wc = (wid & 1) * 64;
  f32x4 acc[4][4] = {};

  for (int kt = 0; kt < K; kt += 32) {
#pragma unroll
    for (int it = 0; it < 2; ++it) {
      const int s = it * 256 + tid;
      const int row = s >> 2, kc = s & 3;
      gload_lds16(&A[(rb + row) * K + kt + kc * 8], &As[s * 8]);
      gload_lds16(&BT[(cbase + row) * K + kt + kc * 8], &Bs[s * 8]);
    }
    __syncthreads();
    short8 a[4], b[4];
#pragma unroll
    for (int m = 0; m < 4; ++m)
      a[m] = *(const short8*)&As[(wr + m * 16 + l15) * 32 + g * 8];
#pragma unroll
    for (int n = 0; n < 4; ++n)
      b[n] = *(const short8*)&Bs[(wc + n * 16 + l15) * 32 + g * 8];
#pragma unroll
    for (int m = 0; m < 4; ++m)
#pragma unroll
      for (int n = 0; n < 4; ++n)
        acc[m][n] = mfma_s8(a[m], b[n], acc[m][n]);
    __syncthreads();
  }

#pragma unroll
  for (int n = 0; n < 4; ++n) {
    const int col = (int)cbase + wc + n * 16 + l15;
    const float bv = bias[col];
#pragma unroll
    for (int m = 0; m < 4; ++m) {
#pragma unroll
      for (int r = 0; r < 4; ++r) {
        const int row = (int)rb + wr + m * 16 + g * 4 + r;
        float v = acc[m][n][r] + bv;
        v = fmaxf(v, 0.f);
        C[(size_t)row * N + col] = f2bf(v);
      }
    }
  }
}

// ---------- uni MLPs + final layer (H1 @ W2^T), 8 chunks ----------
// grid = 1024: blockIdx = rowblk*8 + chunk. 4 waves x 32 batch rows (2 frags).
// Weight blobs are DOUBLE-BUFFERED IN LDS via global_load_lds (one 16B stage
// instr per thread = whole 4096B blob): while all 4 waves compute feature ii
// from wbuf[ii&1], the block stages feature ii+1 into wbuf[(ii+1)&1].
// __syncthreads() is the phase boundary (drains vmcnt). Weight reads become
// broadcast ds_read_b128 -- off the global-latency critical path entirely.
// All MFMAs operand-swapped: D[out][batch]; b = lane&15, out = 4*(lane>>4)+r.
// ub2 folded into the layer-2 MFMA accumulator init.
__global__ __launch_bounds__(256, 4) void k_uni(
    const float* __restrict__ x,
    const char* __restrict__ uwp,
    const u16* __restrict__ H1, const u16* __restrict__ W2T,
    float* __restrict__ part)
{
  const int tid = threadIdx.x, lane = tid & 63, wid = tid >> 6;
  const int l15 = lane & 15, g = lane >> 4;
  const int chunk = blockIdx.x & 7, rowblk = blockIdx.x >> 3;
  const int rb_blk = rowblk * 128;
  const int rb = rb_blk + wid * 32;
  const int i0 = chunk * 32;

  __shared__ __align__(16) float xt[128][33];   // odd stride: conflict-free
  __shared__ __align__(16) char wbuf[2][4096];  // double-buffered weight blobs

  {
    const int r0 = tid >> 3, c4 = (tid & 7) << 2;
#pragma unroll
    for (int rr = 0; rr < 128; rr += 32)
      *(float4*)&xt[rr + r0][c4] =
          *(const float4*)&x[(size_t)(rb_blk + rr + r0) * NINP + i0 + c4];
  }
  gload_lds16(uwp + (size_t)i0 * 4096 + tid * 16, &wbuf[0][tid * 16]);
  __syncthreads();

  const f32x4 zero4 = {0.f, 0.f, 0.f, 0.f};
  f32x4 acc0 = zero4, acc1 = zero4;
  const float* xr0 = &xt[wid * 32 + l15][0];
  const float* xr1 = &xt[wid * 32 + 16 + l15][0];

#pragma unroll 2
  for (int ii = 0; ii < 32; ++ii) {
    // stage next feature's blob into the other buffer (fire-and-forget;
    // lands before the __syncthreads at the end of this iteration)
    const int nxt = (ii + 1) & 31;    // ii=31 wraps: redundant but harmless
    gload_lds16(uwp + (size_t)(i0 + nxt) * 4096 + tid * 16,
                &wbuf[(ii + 1) & 1][tid * 16]);

    const char* bp = &wbuf[ii & 1][0];
    const f32x4 w1lo = *(const f32x4*)(bp + g * 32);
    const f32x4 w1hi = *(const f32x4*)(bp + g * 32 + 16);
    const f32x4 b1lo = *(const f32x4*)(bp + 128 + g * 32);
    const f32x4 b1hi = *(const f32x4*)(bp + 128 + g * 32 + 16);
    const f32x4 bb0  = *(const f32x4*)(bp + 256 + g * 16);
    const f32x4 bb1  = *(const f32x4*)(bp + 320 + g * 16);
    const bf16x8 bv0 = *(const bf16x8*)(bp + 512 + lane * 16);
    const bf16x8 bv1 = *(const bf16x8*)(bp + 1536 + lane * 16);
    const bf16x8 b3  = *(const bf16x8*)(bp + 2560 + lane * 16);
    const float xv0 = xr0[ii], xv1 = xr1[ii];

    // layer 1 (rank-1): h1[b][f=g*8+j] as B-frag, two batch frags
    bf16x8 af0, af1;
#pragma unroll
    for (int j = 0; j < 4; ++j) {
      af0[j]     = (__bf16)fmaxf(fmaf(xv0, w1lo[j], b1lo[j]), 0.f);
      af0[4 + j] = (__bf16)fmaxf(fmaf(xv0, w1hi[j], b1hi[j]), 0.f);
      af1[j]     = (__bf16)fmaxf(fmaf(xv1, w1lo[j], b1lo[j]), 0.f);
      af1[4 + j] = (__bf16)fmaxf(fmaf(xv1, w1hi[j], b1hi[j]), 0.f);
    }

    // layer 2 swapped: D2[o][b], o = 4g+r (+16 for d1*), bias in C-input
    const f32x4 d00 = mfma_bb(bv0, af0, bb0);
    const f32x4 d10 = mfma_bb(bv1, af0, bb1);
    const f32x4 d01 = mfma_bb(bv0, af1, bb0);
    const f32x4 d11 = mfma_bb(bv1, af1, bb1);

    // h2 = relu(D2), lane-local; k-slots match uw3p permutation
    bf16x8 h20, h21;
#pragma unroll
    for (int j = 0; j < 4; ++j) {
      h20[j]     = (__bf16)fmaxf(d00[j], 0.f);
      h20[4 + j] = (__bf16)fmaxf(d10[j], 0.f);
      h21[j]     = (__bf16)fmaxf(d01[j], 0.f);
      h21[4 + j] = (__bf16)fmaxf(d11[j], 0.f);
    }

    // layer 3 swapped: acc[o2][b] += uw3p @ h2
    acc0 = mfma_bb(b3, h20, acc0);
    acc1 = mfma_bb(b3, h21, acc1);

    __syncthreads();   // phase boundary: drains vmcnt, next blob is ready
  }

  // final-layer K-chunk (K=128): acc[o2][b] += W2T @ H1^T
  {
    const int kb0 = chunk * 128;
#pragma unroll
    for (int kk = 0; kk < 4; ++kk) {
      const int kb = kb0 + kk * 32;
      const bf16x8 a0 = __builtin_bit_cast(bf16x8,
          *(const i32x4*)&H1[(size_t)(rb + l15) * HID + kb + g * 8]);
      const bf16x8 a1 = __builtin_bit_cast(bf16x8,
          *(const i32x4*)&H1[(size_t)(rb + 16 + l15) * HID + kb + g * 8]);
      const bf16x8 bv = __builtin_bit_cast(bf16x8,
          *(const i32x4*)&W2T[l15 * HID + kb + g * 8]);
      acc0 = mfma_bb(bv, a0, acc0);
      acc1 = mfma_bb(bv, a1, acc1);
    }
  }

  // acc*[r] = u[b=l15(+16)][o2=4g+r] -> contiguous f32x4 stores
  float* p = part + ((size_t)chunk * BATCH + rb) * NOUT;
  *(f32x4*)&p[l15 * 16 + g * 4] = acc0;
  *(f32x4*)&p[(16 + l15) * 16 + g * 4] = acc1;
}

// ---------- reduce 8 partials + cb -> out ----------
__global__ __launch_bounds__(256) void k_reduce(
    const float* __restrict__ part, const float* __restrict__ cb,
    float* __restrict__ out)
{
  const int j4 = blockIdx.x * 256 + threadIdx.x;   // 65536 float4's
  const float4 c = ((const float4*)cb)[j4 & 3];
  const float4* p = (const float4*)part;
  float rx = c.x, ry = c.y, rz = c.z, rw = c.w;
#pragma unroll
  for (int cc = 0; cc < 8; ++cc) {
    const float4 a = p[cc * 65536 + j4];
    rx += a.x; ry += a.y; rz += a.z; rw += a.w;
  }
  float4 r; r.x = rx; r.y = ry; r.z = rz; r.w = rw;
  ((float4*)out)[j4] = r;
}

extern "C" void kernel_launch(void* const* d_in, const int* in_sizes, int n_in,
                              void* d_out, int out_size, void* d_ws, size_t ws_size,
                              hipStream_t stream) {
  (void)in_sizes; (void)n_in; (void)out_size; (void)ws_size;
  const float* x   = (const float*)d_in[0];
  const float* W0  = (const float*)d_in[1];
  const float* b0  = (const float*)d_in[2];
  const float* W1  = (const float*)d_in[3];
  const float* b1  = (const float*)d_in[4];
  const float* W2  = (const float*)d_in[5];
  const float* b2  = (const float*)d_in[6];
  const float* uw1 = (const float*)d_in[7];
  const float* ub1 = (const float*)d_in[8];
  const float* uw2 = (const float*)d_in[9];
  const float* ub2 = (const float*)d_in[10];
  const float* uw3 = (const float*)d_in[11];
  const float* ub3 = (const float*)d_in[12];
  float* out = (float*)d_out;

  char* ws = (char*)d_ws;
  u16*   H0   = (u16*)(ws + OFF_H0);
  u16*   H1   = (u16*)(ws + OFF_H1);
  u16*   xb   = (u16*)(ws + OFF_XB);
  u16*   W0T  = (u16*)(ws + OFF_W0T);
  u16*   W1T  = (u16*)(ws + OFF_W1T);
  u16*   W2T  = (u16*)(ws + OFF_W2T);
  char*  uwp  = (char*)(ws + OFF_UWP);
  float* cb   = (float*)(ws + OFF_CB);
  float* part = (float*)(ws + OFF_PART);

  k_prep<<<5817, 256, 0, stream>>>(x, W0, W1, W2, uw1, ub1, uw2, ub2, uw3,
                                   b2, ub3, xb, W0T, W1T, W2T, uwp, cb);
  k_gemm<<<1024, 256, 0, stream>>>(xb, W0T, b0, H0, BATCH, HID, NINP);
  k_gemm<<<1024, 256, 0, stream>>>(H0, W1T, b1, H1, BATCH, HID, HID);
  k_uni<<<1024, 256, 0, stream>>>(x, uwp, H1, W2T, part);
  k_reduce<<<256, 256, 0, stream>>>(part, cb, out);
}